// Round 18
// baseline (364.188 us; speedup 1.0000x reference)
//
#include <hip/hip_runtime.h>
#include <hip/hip_bf16.h>
#include <math.h>
#include <stdint.h>

typedef __attribute__((ext_vector_type(8))) short bf16x8;
typedef __attribute__((ext_vector_type(4))) float floatx4;

static __device__ __forceinline__ unsigned short f32_to_bf16_rne(float f) {
    union { float f; uint32_t u; } v; v.f = f;
    uint32_t u = v.u;
    return (unsigned short)((u + 0x7fffu + ((u >> 16) & 1u)) >> 16);
}
static __device__ __forceinline__ float bf16_to_f32(unsigned short h) {
    union { uint32_t u; float f; } v; v.u = ((uint32_t)h) << 16;
    return v.f;
}
// 8 fp32 (two float4-vectors) -> bf16x8 via HW v_cvt_pk_bf16_f32 (RNE)
static __device__ __forceinline__ bf16x8 cvt8(floatx4 a, floatx4 b) {
    union { __hip_bfloat162 h[4]; bf16x8 v; } u;
    u.h[0] = __float22bfloat162_rn({a[0], a[1]});
    u.h[1] = __float22bfloat162_rn({a[2], a[3]});
    u.h[2] = __float22bfloat162_rn({b[0], b[1]});
    u.h[3] = __float22bfloat162_rn({b[2], b[3]});
    return u.v;
}

// ---------------------------------------------------------------------------
// Prep: W1a (50x318) -> hi/lo bf16, fragment-ordered (ks-major):
// byte = ks*8192 + p*4096 + kq*1024 + n*16  (n in [0,64); k>=318 zeroed --
// those zeros also neutralize the A-side row-spill at k=318,319)
// ---------------------------------------------------------------------------
__global__ void prep_w(const float* __restrict__ W1a, unsigned short* __restrict__ Bpre) {
    int idx = blockIdx.x * 256 + threadIdx.x;
    if (idx >= 40960) return;
    int e  = idx & 7;
    int n  = (idx >> 3) & 63;
    int kq = (idx >> 9) & 3;
    int p  = (idx >> 11) & 1;
    int ks = idx >> 12;
    int k  = ks * 32 + kq * 8 + e;
    float w = (n < 50 && k < 318) ? W1a[n * 318 + k] : 0.0f;
    unsigned short hi = f32_to_bf16_rne(w);
    Bpre[idx] = (p == 0) ? hi : f32_to_bf16_rne(w - bf16_to_f32(hi));
}

// ---------------------------------------------------------------------------
// Kernel A (GEMM, gll-staged): 8192 blocks (one 64-token slab), 256 threads
// (4 n-sliced waves), 3 blocks/CU (LDS 40960). x staged LINEARLY as raw f32
// into two 20.5KB LDS quarter-buffers via width-16 global_load_lds (zero
// staging VGPRs, 1KB dense per instruction). Per quarter: counted vmcnt(4)
// + one raw lgkm barrier; fragments read from LDS (2x ds_read_b128), cvt_pk
// in-register, 20 MFMA into one 4-VGPR acc; h1 stored quarter-wise.
// B hi/lo register-resident per wave n-slice (80 VGPR, loaded once from L2).
// ---------------------------------------------------------------------------
#define SLABB 81408      // slab bytes (64*318*4)
#define QDATA 20352      // quarter data bytes (16 rows)
#define QSTG  20480      // staged bytes per quarter (20 x 1KB wave-chunks)
#define H1S   52         // h1 global row stride (floats)

#define GLL(g, l) __builtin_amdgcn_global_load_lds( \
    (const __attribute__((address_space(1))) void*)(g), \
    (__attribute__((address_space(3))) void*)(l), 16, 0, 0)

__global__ __launch_bounds__(256, 3)
void gemm_h1(const float* __restrict__ x,
             const unsigned short* __restrict__ Bpre,
             const float* __restrict__ b1a,
             float* __restrict__ h1g)
{
    __shared__ __align__(1024) char sbuf[2 * QSTG];   // 40,960 B

    const int tid  = threadIdx.x;
    const int wv   = tid >> 6;
    const int lane = tid & 63;
    const int fr   = lane & 15;
    const int kq   = lane >> 4;

    const size_t slab = blockIdx.x;
    const char* xs = (const char*)x + slab * SLABB;
    const char* xclamp = (const char*)x + 666894336 - 16;   // last aligned 16B

    // ---- B hi/lo fragments, register-resident (wave's n-slice [16wv,16wv+16))
    bf16x8 Bh[10], Bl[10];
    {
        const char* bb = (const char*)Bpre + (kq << 10) + ((wv * 16 + fr) << 4);
        #pragma unroll
        for (int ks = 0; ks < 10; ++ks) {
            Bh[ks] = *(const bf16x8*)(bb + ks * 8192);
            Bl[ks] = *(const bf16x8*)(bb + ks * 8192 + 4096);
        }
    }
    const int n = wv * 16 + fr;
    const float bia = (n < 50) ? b1a[n] : 0.0f;

    // stage quarter q into buffer half b (5 x width-16 gll per wave)
#define STAGE(b, q) { \
    char* lb = sbuf + (b) * QSTG + wv * 1024; \
    const char* gs = xs + (size_t)(q) * QDATA + wv * 1024 + lane * 16; \
    _Pragma("unroll") for (int j = 0; j < 5; ++j) { \
        const char* g = gs + j * 4096; \
        if (g > xclamp) g = xclamp; \
        GLL(g, lb + j * 4096); \
    } }

#define WAITBAR(NSTR) do { \
    asm volatile("s_waitcnt vmcnt(" NSTR ")" ::: "memory"); \
    __builtin_amdgcn_s_barrier(); \
    __builtin_amdgcn_sched_barrier(0); } while (0)

#define COMPUTE(b, q) { \
    floatx4 acc = (floatx4){0.f, 0.f, 0.f, 0.f}; \
    const char* ab = sbuf + (b) * QSTG + fr * 1272 + kq * 32; \
    _Pragma("unroll") for (int ks = 0; ks < 10; ++ks) { \
        floatx4 lo = *(const floatx4*)(ab + ks * 128); \
        floatx4 hi = *(const floatx4*)(ab + ks * 128 + 16); \
        bf16x8 a = cvt8(lo, hi); \
        acc = __builtin_amdgcn_mfma_f32_16x16x32_bf16(a, Bh[ks], acc, 0, 0, 0); \
        acc = __builtin_amdgcn_mfma_f32_16x16x32_bf16(a, Bl[ks], acc, 0, 0, 0); \
    } \
    if (n < 50) { \
        float* hrow = h1g + ((slab * 64 + (q) * 16 + kq * 4) * H1S) + n; \
        _Pragma("unroll") for (int r = 0; r < 4; ++r) \
            hrow[r * H1S] = fmaxf(acc[r] + bia, 0.0f); \
    } }

    // ---- prologue: stage q0; drain everything once; barrier
    STAGE(0, 0);
    WAITBAR("0");                 // B regs + q0 staged

    // ---- q0: issue q1, compute q0
    STAGE(1, 1);
    COMPUTE(0, 0);                // 4 stores issued after the 5 gll

    // ---- q1: wait stage(q1) (4 younger stores allowed), bar, issue q2
    WAITBAR("4");
    STAGE(0, 2);
    COMPUTE(1, 1);

    // ---- q2
    WAITBAR("4");
    STAGE(1, 3);
    COMPUTE(0, 2);

    // ---- q3
    WAITBAR("4");
    COMPUTE(1, 3);
#undef STAGE
#undef WAITBAR
#undef COMPUTE
}

// ---------------------------------------------------------------------------
// Kernel T: tail. 2048 blocks x 256 threads; thread = token; wave = one
// 64-token slab. layer2/3 + score + wave softmax partial {m,S,V[20]} -> ws.
// ---------------------------------------------------------------------------
__global__ __launch_bounds__(256, 4)
void tail_pool(const float* __restrict__ h1g,
               const float* __restrict__ W1b, const float* __restrict__ b1b,
               const float* __restrict__ W1c, const float* __restrict__ b1c,
               const float* __restrict__ pW1, const float* __restrict__ pb1,
               const float* __restrict__ pW2, const float* __restrict__ pb2,
               float* __restrict__ partials)
{
    const int t    = blockIdx.x * 256 + threadIdx.x;   // global token id
    const int lane = threadIdx.x & 63;

    float hv[52];
    {
        const float4* hr = (const float4*)(h1g + (size_t)t * H1S);
        #pragma unroll
        for (int j = 0; j < 13; ++j) {
            float4 u = hr[j];
            hv[4 * j] = u.x; hv[4 * j + 1] = u.y;
            hv[4 * j + 2] = u.z; hv[4 * j + 3] = u.w;
        }
    }

    float h2[20];
    #pragma unroll
    for (int o = 0; o < 20; ++o) h2[o] = b1b[o];
    #pragma unroll
    for (int i = 0; i < 50; ++i) {
        float hvv = hv[i];
        #pragma unroll
        for (int o = 0; o < 20; ++o) h2[o] = fmaf(hvv, W1b[o * 50 + i], h2[o]);
    }
    #pragma unroll
    for (int o = 0; o < 20; ++o) h2[o] = fmaxf(h2[o], 0.0f);

    float h3[20];
    #pragma unroll
    for (int o = 0; o < 20; ++o) {
        float a = b1c[o];
        const float* w = W1c + o * 20;
        #pragma unroll
        for (int i = 0; i < 20; ++i) a = fmaf(h2[i], w[i], a);
        h3[o] = fmaxf(a, 0.0f);
    }

    float s = pb2[0];
    #pragma unroll
    for (int j = 0; j < 10; ++j) {
        float a = pb1[j];
        const float* w = pW1 + j * 20;
        #pragma unroll
        for (int i = 0; i < 20; ++i) a = fmaf(h3[i], w[i], a);
        s = fmaf(fmaxf(a, 0.0f), pW2[j], s);
    }

    float m = s;
    #pragma unroll
    for (int d = 32; d > 0; d >>= 1) m = fmaxf(m, __shfl_xor(m, d));
    float e = expf(s - m);
    float S = e;
    #pragma unroll
    for (int d = 32; d > 0; d >>= 1) S += __shfl_xor(S, d);

    float V[20];
    #pragma unroll
    for (int o = 0; o < 20; ++o) {
        float v = e * h3[o];
        #pragma unroll
        for (int d = 32; d > 0; d >>= 1) v += __shfl_xor(v, d);
        V[o] = v;
    }

    float myv = m;
    if (lane == 1) myv = S;
    #pragma unroll
    for (int o = 0; o < 20; ++o) if (lane == o + 2) myv = V[o];
    if (lane < 22) partials[(size_t)(t >> 6) * 24 + lane] = myv;
}

// ---------------------------------------------------------------------------
// Kernel B: combine half-group partials, pool over G=128, normalize, head.
// ---------------------------------------------------------------------------
__global__ __launch_bounds__(128, 4)
void pool_g_head(const float* __restrict__ partials,
                 const float* __restrict__ qW1, const float* __restrict__ qb1,
                 const float* __restrict__ qW2, const float* __restrict__ qb2,
                 const float* __restrict__ W3a, const float* __restrict__ b3a,
                 const float* __restrict__ W3b, const float* __restrict__ b3b,
                 float* __restrict__ out)
{
    __shared__ float red_m[2];
    __shared__ float red_s[2];
    __shared__ float part[2][20];

    const int tid = threadIdx.x;      // g
    const int b = blockIdx.x;
    const float* P = partials + ((size_t)(b * 128 + tid)) * 48;

    float m0 = P[0], S0 = P[1], m1 = P[24], S1 = P[25];
    float m = fmaxf(m0, m1);
    float w0 = expf(m0 - m), w1 = expf(m1 - m);
    float den = fmaf(S0, w0, S1 * w1);

    float v[20];
    #pragma unroll
    for (int o = 0; o < 20; ++o)
        v[o] = fmaf(P[2 + o], w0, P[26 + o] * w1) / den;

    float s = qb2[0];
    #pragma unroll
    for (int j = 0; j < 10; ++j) {
        float a = qb1[j];
        const float* w = qW1 + j * 20;
        #pragma unroll
        for (int i = 0; i < 20; ++i) a = fmaf(v[i], w[i], a);
        s = fmaf(fmaxf(a, 0.0f), qW2[j], s);
    }

    const int wig = tid >> 6, lane = tid & 63;
    float mm = s;
    #pragma unroll
    for (int d = 32; d > 0; d >>= 1) mm = fmaxf(mm, __shfl_xor(mm, d));
    if (lane == 0) red_m[wig] = mm;
    __syncthreads();
    mm = fmaxf(red_m[0], red_m[1]);

    float e = expf(s - mm);
    float su = e;
    #pragma unroll
    for (int d = 32; d > 0; d >>= 1) su += __shfl_xor(su, d);
    if (lane == 0) red_s[wig] = su;

    #pragma unroll
    for (int o = 0; o < 20; ++o) {
        float val = e * v[o];
        #pragma unroll
        for (int d = 32; d > 0; d >>= 1) val += __shfl_xor(val, d);
        if (lane == 0) part[wig][o] = val;
    }
    __syncthreads();

    if (tid == 0) {
        float dg = red_s[0] + red_s[1];
        float rb[20];
        float n2 = 0.0f;
        #pragma unroll
        for (int o = 0; o < 20; ++o) {
            rb[o] = (part[0][o] + part[1][o]) / dg;
            n2 = fmaf(rb[o], rb[o], n2);
        }
        float nrm = fmaxf(sqrtf(n2), 1e-12f);
        #pragma unroll
        for (int o = 0; o < 20; ++o) rb[o] /= nrm;

        float accv = b3b[0];
        #pragma unroll
        for (int j = 0; j < 10; ++j) {
            float a = b3a[j];
            const float* w = W3a + j * 20;
            #pragma unroll
            for (int i = 0; i < 20; ++i) a = fmaf(rb[i], w[i], a);
            accv = fmaf(fmaxf(a, 0.0f), W3b[j], accv);
        }
        out[b] = accv;
    }
}

extern "C" void kernel_launch(void* const* d_in, const int* in_sizes, int n_in,
                              void* d_out, int out_size, void* d_ws, size_t ws_size,
                              hipStream_t stream) {
    const float* x   = (const float*)d_in[0];
    const float* W1a = (const float*)d_in[1];
    const float* b1a = (const float*)d_in[2];
    const float* W1b = (const float*)d_in[3];
    const float* b1b = (const float*)d_in[4];
    const float* W1c = (const float*)d_in[5];
    const float* b1c = (const float*)d_in[6];
    const float* pW1 = (const float*)d_in[7];
    const float* pb1 = (const float*)d_in[8];
    const float* pW2 = (const float*)d_in[9];
    const float* pb2 = (const float*)d_in[10];
    const float* qW1 = (const float*)d_in[11];
    const float* qb1 = (const float*)d_in[12];
    const float* qW2 = (const float*)d_in[13];
    const float* qb2 = (const float*)d_in[14];
    const float* W3a = (const float*)d_in[15];
    const float* b3a = (const float*)d_in[16];
    const float* W3b = (const float*)d_in[17];
    const float* b3b = (const float*)d_in[18];

    float* partials      = (float*)d_ws;                              // 786,432 B
    unsigned short* Bpre = (unsigned short*)((char*)d_ws + 786432);   // 81,920 B
    float* h1g           = (float*)((char*)d_ws + 868352);            // 109 MB

    prep_w<<<160, 256, 0, stream>>>(W1a, Bpre);
    gemm_h1<<<8192, 256, 0, stream>>>(x, Bpre, b1a, h1g);
    tail_pool<<<2048, 256, 0, stream>>>(
        h1g, W1b, b1b, W1c, b1c, pW1, pb1, pW2, pb2, partials);
    pool_g_head<<<32, 128, 0, stream>>>(
        partials, qW1, qb1, qW2, qb2, W3a, b3a, W3b, b3b, (float*)d_out);
}

// Round 19
// 223.751 us; speedup vs baseline: 1.6276x; 1.6276x over previous
//
#include <hip/hip_runtime.h>
#include <hip/hip_bf16.h>
#include <math.h>
#include <stdint.h>

typedef __attribute__((ext_vector_type(8))) short bf16x8;
typedef __attribute__((ext_vector_type(4))) float floatx4;

static __device__ __forceinline__ unsigned short f32_to_bf16_rne(float f) {
    union { float f; uint32_t u; } v; v.f = f;
    uint32_t u = v.u;
    return (unsigned short)((u + 0x7fffu + ((u >> 16) & 1u)) >> 16);
}
static __device__ __forceinline__ float bf16_to_f32(unsigned short h) {
    union { uint32_t u; float f; } v; v.u = ((uint32_t)h) << 16;
    return v.f;
}
// 8 fp32 (two float4) -> bf16x8 via HW v_cvt_pk_bf16_f32 (RNE)
static __device__ __forceinline__ bf16x8 cvt8(float4 a, float4 b) {
    union { __hip_bfloat162 h[4]; bf16x8 v; } u;
    u.h[0] = __float22bfloat162_rn({a.x, a.y});
    u.h[1] = __float22bfloat162_rn({a.z, a.w});
    u.h[2] = __float22bfloat162_rn({b.x, b.y});
    u.h[3] = __float22bfloat162_rn({b.z, b.w});
    return u.v;
}

// LDS-correct barrier that does NOT drain vmcnt (A-burst stays in flight).
#define BAR() do { \
    asm volatile("s_waitcnt lgkmcnt(0)" ::: "memory"); \
    __builtin_amdgcn_s_barrier(); \
    asm volatile("" ::: "memory"); } while (0)

// ---------------------------------------------------------------------------
// Prep: W1a (50x318) -> hi/lo bf16, fragment-ordered (ks-major):
// byte = ks*8192 + p*4096 + kq*1024 + n*16  (n in [0,64), zero-padded)
// ---------------------------------------------------------------------------
__global__ void prep_w(const float* __restrict__ W1a, unsigned short* __restrict__ Bpre) {
    int idx = blockIdx.x * 256 + threadIdx.x;
    if (idx >= 40960) return;
    int e  = idx & 7;
    int n  = (idx >> 3) & 63;
    int kq = (idx >> 9) & 3;
    int p  = (idx >> 11) & 1;
    int ks = idx >> 12;
    int k  = ks * 32 + kq * 8 + e;
    float w = (n < 50 && k < 318) ? W1a[n * 318 + k] : 0.0f;
    unsigned short hi = f32_to_bf16_rne(w);
    Bpre[idx] = (p == 0) ? hi : f32_to_bf16_rne(w - bf16_to_f32(hi));
}

// ---------------------------------------------------------------------------
// Kernel A (pure GEMM, r16 structure): 8192 blocks (64-token slab), 256
// threads (4 m-sliced waves), 3 blocks/CU (LDS 40960). A: ONE pinned 20x
// float4 burst direct global->reg (rides across all barriers). B: two 40KB
// K-half stages through LDS; half-1 loads issued before the first barrier.
// 3 lgkm-only barriers. NEW: h1 stored as bf16 token-pair-packed u32:
// h1b[tp*52 + n] = {token 2tp (lo16), token 2tp+1 (hi16)} at column n.
// r-adjacent tokens are in-lane -> pack needs no cross-lane ops; 16 fr-lanes
// still store 64B-contiguous segments. Halves the h1 round-trip (218->109MB).
// ---------------------------------------------------------------------------
#define SLAB (64 * 318)
#define H1W 52     // h1b row stride in u32 words (50 data + 2 pad, 208 B)

__global__ __launch_bounds__(256, 3)
void gemm_h1(const float* __restrict__ x,
             const unsigned short* __restrict__ Bpre,
             const float* __restrict__ b1a,
             uint32_t* __restrict__ h1b)
{
    __shared__ __align__(16) char bsm[40960];   // one B K-half image

    const int tid  = threadIdx.x;
    const int wv   = tid >> 6;
    const int lane = tid & 63;
    const int fr   = lane & 15;
    const int kq   = lane >> 4;

    const float* arow = x + (size_t)blockIdx.x * SLAB + (wv * 16 + fr) * 318 + kq * 8;

    // ---- issue B half-0 loads first (oldest), then the FULL A burst
    floatx4 gb[10];
    #pragma unroll
    for (int j = 0; j < 10; ++j)
        gb[j] = *(const floatx4*)((const char*)Bpre + (j * 256 + tid) * 16);

    float4 af[20];
    #pragma unroll
    for (int ks = 0; ks < 10; ++ks)
        #pragma unroll
        for (int j = 0; j < 2; ++j) {
            if (ks == 9 && kq == 3 && j == 1) {     // k=316..319: pad 318,319
                float2 t = *(const float2*)(arow + 9 * 32 + 4);
                af[19] = make_float4(t.x, t.y, 0.f, 0.f);
            } else {
                af[ks * 2 + j] = *(const float4*)(arow + ks * 32 + 4 * j);
            }
        }
    __builtin_amdgcn_sched_barrier(0);   // pin all load issue above

    // write half-0 to LDS (waits only the B loads; A stays in flight),
    // then issue half-1 B loads (latency hides under pass 1)
    #pragma unroll
    for (int j = 0; j < 10; ++j)
        *(floatx4*)(bsm + (j * 256 + tid) * 16) = gb[j];
    #pragma unroll
    for (int j = 0; j < 10; ++j)
        gb[j] = *(const floatx4*)((const char*)Bpre + 40960 + (j * 256 + tid) * 16);
    __builtin_amdgcn_sched_barrier(0);
    BAR();   // half-0 visible; A-burst + half-1 loads still outstanding

    floatx4 acc[4];
    #pragma unroll
    for (int nf = 0; nf < 4; ++nf) acc[nf] = (floatx4){0.f, 0.f, 0.f, 0.f};

    // ---- pass 1: ks 0..4
    #pragma unroll
    for (int ks = 0; ks < 5; ++ks) {
        const char* bb = bsm + ks * 8192 + (kq << 10) + (fr << 4);
        bf16x8 a = cvt8(af[ks * 2], af[ks * 2 + 1]);
        #pragma unroll
        for (int nf = 0; nf < 4; ++nf) {
            bf16x8 bh = *(const bf16x8*)(bb + nf * 256);
            bf16x8 bl = *(const bf16x8*)(bb + 4096 + nf * 256);
            acc[nf] = __builtin_amdgcn_mfma_f32_16x16x32_bf16(a, bh, acc[nf], 0, 0, 0);
            acc[nf] = __builtin_amdgcn_mfma_f32_16x16x32_bf16(a, bl, acc[nf], 0, 0, 0);
        }
    }
    BAR();   // all waves done reading half-0

    #pragma unroll
    for (int j = 0; j < 10; ++j)
        *(floatx4*)(bsm + (j * 256 + tid) * 16) = gb[j];   // half-1 (already landed)
    BAR();   // half-1 visible

    // ---- pass 2: ks 5..9
    #pragma unroll
    for (int ks = 5; ks < 10; ++ks) {
        const char* bb = bsm + (ks - 5) * 8192 + (kq << 10) + (fr << 4);
        bf16x8 a = cvt8(af[ks * 2], af[ks * 2 + 1]);
        #pragma unroll
        for (int nf = 0; nf < 4; ++nf) {
            bf16x8 bh = *(const bf16x8*)(bb + nf * 256);
            bf16x8 bl = *(const bf16x8*)(bb + 4096 + nf * 256);
            acc[nf] = __builtin_amdgcn_mfma_f32_16x16x32_bf16(a, bh, acc[nf], 0, 0, 0);
            acc[nf] = __builtin_amdgcn_mfma_f32_16x16x32_bf16(a, bl, acc[nf], 0, 0, 0);
        }
    }

    // ---- bias + ReLU -> h1b bf16 token-pair-packed
    // lane (fr,kq): acc[nf][r] = h1[token kq*4+r][n = nf*16+fr]
    {
        const size_t tp0 = (size_t)blockIdx.x * 32 + wv * 8 + kq * 2;
        uint32_t* hw = h1b + tp0 * H1W;
        #pragma unroll
        for (int nf = 0; nf < 4; ++nf) {
            int n = nf * 16 + fr;
            if (n < 50) {
                float bia = b1a[n];
                float v0 = fmaxf(acc[nf][0] + bia, 0.0f);
                float v1 = fmaxf(acc[nf][1] + bia, 0.0f);
                float v2 = fmaxf(acc[nf][2] + bia, 0.0f);
                float v3 = fmaxf(acc[nf][3] + bia, 0.0f);
                hw[n]       = (uint32_t)f32_to_bf16_rne(v0) | ((uint32_t)f32_to_bf16_rne(v1) << 16);
                hw[H1W + n] = (uint32_t)f32_to_bf16_rne(v2) | ((uint32_t)f32_to_bf16_rne(v3) << 16);
            }
        }
    }
}

// ---------------------------------------------------------------------------
// Kernel T: tail. 2048 blocks x 256 threads; thread = token; wave = one
// 64-token slab. Reads bf16 token-pair-packed h1b (25 aligned uint2/thread,
// extract by (t&1)*16 shift). layer2/3 + score + wave softmax partial -> ws.
// ---------------------------------------------------------------------------
__global__ __launch_bounds__(256, 4)
void tail_pool(const uint32_t* __restrict__ h1b,
               const float* __restrict__ W1b, const float* __restrict__ b1b,
               const float* __restrict__ W1c, const float* __restrict__ b1c,
               const float* __restrict__ pW1, const float* __restrict__ pb1,
               const float* __restrict__ pW2, const float* __restrict__ pb2,
               float* __restrict__ partials)
{
    const int t    = blockIdx.x * 256 + threadIdx.x;   // global token id
    const int lane = threadIdx.x & 63;
    const int sh   = (t & 1) * 16;

    float hv[50];
    {
        const uint2* hr = (const uint2*)(h1b + (size_t)(t >> 1) * H1W);
        #pragma unroll
        for (int j = 0; j < 25; ++j) {
            uint2 u = hr[j];
            hv[2 * j]     = bf16_to_f32((unsigned short)(u.x >> sh));
            hv[2 * j + 1] = bf16_to_f32((unsigned short)(u.y >> sh));
        }
    }

    float h2[20];
    #pragma unroll
    for (int o = 0; o < 20; ++o) h2[o] = b1b[o];
    #pragma unroll
    for (int i = 0; i < 50; ++i) {
        float hvv = hv[i];
        #pragma unroll
        for (int o = 0; o < 20; ++o) h2[o] = fmaf(hvv, W1b[o * 50 + i], h2[o]);
    }
    #pragma unroll
    for (int o = 0; o < 20; ++o) h2[o] = fmaxf(h2[o], 0.0f);

    float h3[20];
    #pragma unroll
    for (int o = 0; o < 20; ++o) {
        float a = b1c[o];
        const float* w = W1c + o * 20;
        #pragma unroll
        for (int i = 0; i < 20; ++i) a = fmaf(h2[i], w[i], a);
        h3[o] = fmaxf(a, 0.0f);
    }

    float s = pb2[0];
    #pragma unroll
    for (int j = 0; j < 10; ++j) {
        float a = pb1[j];
        const float* w = pW1 + j * 20;
        #pragma unroll
        for (int i = 0; i < 20; ++i) a = fmaf(h3[i], w[i], a);
        s = fmaf(fmaxf(a, 0.0f), pW2[j], s);
    }

    float m = s;
    #pragma unroll
    for (int d = 32; d > 0; d >>= 1) m = fmaxf(m, __shfl_xor(m, d));
    float e = expf(s - m);
    float S = e;
    #pragma unroll
    for (int d = 32; d > 0; d >>= 1) S += __shfl_xor(S, d);

    float V[20];
    #pragma unroll
    for (int o = 0; o < 20; ++o) {
        float v = e * h3[o];
        #pragma unroll
        for (int d = 32; d > 0; d >>= 1) v += __shfl_xor(v, d);
        V[o] = v;
    }

    float myv = m;
    if (lane == 1) myv = S;
    #pragma unroll
    for (int o = 0; o < 20; ++o) if (lane == o + 2) myv = V[o];
    if (lane < 22) partials[(size_t)(t >> 6) * 24 + lane] = myv;
}

// ---------------------------------------------------------------------------
// Kernel B: combine half-group partials, pool over G=128, normalize, head.
// ---------------------------------------------------------------------------
__global__ __launch_bounds__(128, 4)
void pool_g_head(const float* __restrict__ partials,
                 const float* __restrict__ qW1, const float* __restrict__ qb1,
                 const float* __restrict__ qW2, const float* __restrict__ qb2,
                 const float* __restrict__ W3a, const float* __restrict__ b3a,
                 const float* __restrict__ W3b, const float* __restrict__ b3b,
                 float* __restrict__ out)
{
    __shared__ float red_m[2];
    __shared__ float red_s[2];
    __shared__ float part[2][20];

    const int tid = threadIdx.x;      // g
    const int b = blockIdx.x;
    const float* P = partials + ((size_t)(b * 128 + tid)) * 48;

    float m0 = P[0], S0 = P[1], m1 = P[24], S1 = P[25];
    float m = fmaxf(m0, m1);
    float w0 = expf(m0 - m), w1 = expf(m1 - m);
    float den = fmaf(S0, w0, S1 * w1);

    float v[20];
    #pragma unroll
    for (int o = 0; o < 20; ++o)
        v[o] = fmaf(P[2 + o], w0, P[26 + o] * w1) / den;

    float s = qb2[0];
    #pragma unroll
    for (int j = 0; j < 10; ++j) {
        float a = qb1[j];
        const float* w = qW1 + j * 20;
        #pragma unroll
        for (int i = 0; i < 20; ++i) a = fmaf(v[i], w[i], a);
        s = fmaf(fmaxf(a, 0.0f), qW2[j], s);
    }

    const int wig = tid >> 6, lane = tid & 63;
    float mm = s;
    #pragma unroll
    for (int d = 32; d > 0; d >>= 1) mm = fmaxf(mm, __shfl_xor(mm, d));
    if (lane == 0) red_m[wig] = mm;
    __syncthreads();
    mm = fmaxf(red_m[0], red_m[1]);

    float e = expf(s - mm);
    float su = e;
    #pragma unroll
    for (int d = 32; d > 0; d >>= 1) su += __shfl_xor(su, d);
    if (lane == 0) red_s[wig] = su;

    #pragma unroll
    for (int o = 0; o < 20; ++o) {
        float val = e * v[o];
        #pragma unroll
        for (int d = 32; d > 0; d >>= 1) val += __shfl_xor(val, d);
        if (lane == 0) part[wig][o] = val;
    }
    __syncthreads();

    if (tid == 0) {
        float dg = red_s[0] + red_s[1];
        float rb[20];
        float n2 = 0.0f;
        #pragma unroll
        for (int o = 0; o < 20; ++o) {
            rb[o] = (part[0][o] + part[1][o]) / dg;
            n2 = fmaf(rb[o], rb[o], n2);
        }
        float nrm = fmaxf(sqrtf(n2), 1e-12f);
        #pragma unroll
        for (int o = 0; o < 20; ++o) rb[o] /= nrm;

        float accv = b3b[0];
        #pragma unroll
        for (int j = 0; j < 10; ++j) {
            float a = b3a[j];
            const float* w = W3a + j * 20;
            #pragma unroll
            for (int i = 0; i < 20; ++i) a = fmaf(rb[i], w[i], a);
            accv = fmaf(fmaxf(a, 0.0f), W3b[j], accv);
        }
        out[b] = accv;
    }
}

extern "C" void kernel_launch(void* const* d_in, const int* in_sizes, int n_in,
                              void* d_out, int out_size, void* d_ws, size_t ws_size,
                              hipStream_t stream) {
    const float* x   = (const float*)d_in[0];
    const float* W1a = (const float*)d_in[1];
    const float* b1a = (const float*)d_in[2];
    const float* W1b = (const float*)d_in[3];
    const float* b1b = (const float*)d_in[4];
    const float* W1c = (const float*)d_in[5];
    const float* b1c = (const float*)d_in[6];
    const float* pW1 = (const float*)d_in[7];
    const float* pb1 = (const float*)d_in[8];
    const float* pW2 = (const float*)d_in[9];
    const float* pb2 = (const float*)d_in[10];
    const float* qW1 = (const float*)d_in[11];
    const float* qb1 = (const float*)d_in[12];
    const float* qW2 = (const float*)d_in[13];
    const float* qb2 = (const float*)d_in[14];
    const float* W3a = (const float*)d_in[15];
    const float* b3a = (const float*)d_in[16];
    const float* W3b = (const float*)d_in[17];
    const float* b3b = (const float*)d_in[18];

    float* partials      = (float*)d_ws;                              // 786,432 B
    unsigned short* Bpre = (unsigned short*)((char*)d_ws + 786432);   // 81,920 B
    uint32_t* h1b        = (uint32_t*)((char*)d_ws + 868352);         // 54.5 MB

    prep_w<<<160, 256, 0, stream>>>(W1a, Bpre);
    gemm_h1<<<8192, 256, 0, stream>>>(x, Bpre, b1a, h1b);
    tail_pool<<<2048, 256, 0, stream>>>(
        h1b, W1b, b1b, W1c, b1c, pW1, pb1, pW2, pb2, partials);
    pool_g_head<<<32, 128, 0, stream>>>(
        partials, qW1, qb1, qW2, qb2, W3a, b3a, W3b, b3b, (float*)d_out);
}